// Round 10
// baseline (605.740 us; speedup 1.0000x reference)
//
#include <hip/hip_runtime.h>
#include <hip/hip_bf16.h>
#include <math.h>

#define TPB 256
#define BSHIFT 8                 // 256 nodes per bucket
#define BRANGE (1 << BSHIFT)     // == TPB (bucket_place relies on this)
#define CHUNK 8192               // edges per partition block
#define MAXB 512                 // max buckets (N <= 131072)

typedef float f32x4 __attribute__((ext_vector_type(4)));  // native vec for nontemporal ops

// ---------------- Threefry2x32 (exact JAX semantics) ----------------
__host__ __device__ inline void tf2x32(unsigned ks0, unsigned ks1,
                                       unsigned x0, unsigned x1,
                                       unsigned& o0, unsigned& o1) {
  const unsigned ks2 = ks0 ^ ks1 ^ 0x1BD11BDAu;
  unsigned v0 = x0 + ks0, v1 = x1 + ks1;
#define TF_RND(r) { v0 += v1; v1 = (v1 << (r)) | (v1 >> (32 - (r))); v1 ^= v0; }
  TF_RND(13) TF_RND(15) TF_RND(26) TF_RND(6)
  v0 += ks1; v1 += ks2 + 1u;
  TF_RND(17) TF_RND(29) TF_RND(16) TF_RND(24)
  v0 += ks2; v1 += ks0 + 2u;
  TF_RND(13) TF_RND(15) TF_RND(26) TF_RND(6)
  v0 += ks0; v1 += ks1 + 3u;
  TF_RND(17) TF_RND(29) TF_RND(16) TF_RND(24)
  v0 += ks1; v1 += ks2 + 4u;
  TF_RND(13) TF_RND(15) TF_RND(26) TF_RND(6)
  v0 += ks2; v1 += ks0 + 5u;
#undef TF_RND
  o0 = v0; o1 = v1;
}

__device__ __forceinline__ unsigned bits32(unsigned k0, unsigned k1, unsigned idx) {
  unsigned o0, o1;
  tf2x32(k0, k1, 0u, idx, o0, o1);
  return o0 ^ o1;
}

__device__ __forceinline__ float bits_to_u(unsigned bits) {
  float f = __uint_as_float((bits >> 9) | 0x3f800000u) - 1.0f;
  return (f > 0.0f) ? f : 1.17549435e-38f;
}

// exact path: fp64 logs rounded to fp32 at each stage (matches ref staging)
__device__ __forceinline__ float gumbel_exact(unsigned k0, unsigned k1, unsigned idx) {
  float u = bits_to_u(bits32(k0, k1, idx));
  float w = (float)(-log((double)u));
  return (float)(-log((double)w));
}

// fast path: fp32 logs (error ~1e-6 abs; used only when argmax gap is large)
__device__ __forceinline__ float gumbel_fast(unsigned k0, unsigned k1, unsigned idx) {
  float u = bits_to_u(bits32(k0, k1, idx));
  float w = -logf(u);
  return -logf(w);
}

// ---- counting-sort partition: hist -> colscan -> bucketscan -> place ----
__global__ void hist_kernel(const int* __restrict__ dst, int* __restrict__ histT,
                            int E, int nblk, int nbuckets) {
  __shared__ int hist[MAXB];
  for (int i = threadIdx.x; i < nbuckets; i += TPB) hist[i] = 0;
  __syncthreads();
  int beg = blockIdx.x * CHUNK;
  int end = min(beg + CHUNK, E);
  for (int e = beg + threadIdx.x; e < end; e += TPB)
    atomicAdd(&hist[dst[e] >> BSHIFT], 1);
  __syncthreads();
  for (int i = threadIdx.x; i < nbuckets; i += TPB)
    histT[(size_t)i * nblk + blockIdx.x] = hist[i];
}

__global__ void colscan_kernel(int* __restrict__ histT, int* __restrict__ btot, int nblk) {
  __shared__ int sh[MAXB];
  int b = blockIdx.x;
  int t = threadIdx.x;
  sh[t] = (t < nblk) ? histT[(size_t)b * nblk + t] : 0;
  __syncthreads();
  for (int ofs = 1; ofs < MAXB; ofs <<= 1) {
    int v = (t >= ofs) ? sh[t - ofs] : 0;
    __syncthreads();
    sh[t] += v;
    __syncthreads();
  }
  if (t < nblk) histT[(size_t)b * nblk + t] = (t == 0) ? 0 : sh[t - 1];
  if (t == MAXB - 1) btot[b] = sh[MAXB - 1];
}

__global__ void bucketscan_kernel(const int* __restrict__ btot, int* __restrict__ bbase,
                                  int nbuckets, int E) {
  __shared__ int sh[MAXB];
  int t = threadIdx.x;
  sh[t] = (t < nbuckets) ? btot[t] : 0;
  __syncthreads();
  for (int ofs = 1; ofs < MAXB; ofs <<= 1) {
    int v = (t >= ofs) ? sh[t - ofs] : 0;
    __syncthreads();
    sh[t] += v;
    __syncthreads();
  }
  if (t < nbuckets) bbase[t] = (t == 0) ? 0 : sh[t - 1];
  if (t == 0) bbase[nbuckets] = E;
}

__global__ void place_kernel(const int* __restrict__ src, const int* __restrict__ dst,
                             const int* __restrict__ histT, const int* __restrict__ bbase,
                             unsigned* __restrict__ packed, int E, int nblk, int nbuckets) {
  __shared__ int cur[MAXB];
  for (int i = threadIdx.x; i < nbuckets; i += TPB)
    cur[i] = histT[(size_t)i * nblk + blockIdx.x] + bbase[i];
  __syncthreads();
  int beg = blockIdx.x * CHUNK;
  int end = min(beg + CHUNK, E);
  for (int e = beg + threadIdx.x; e < end; e += TPB) {
    int s = src[e], d = dst[e];
    int b = d >> BSHIFT;
    int pos = atomicAdd(&cur[b], 1);        // LDS atomic only
    packed[pos] = (unsigned)s | ((unsigned)(d & (BRANGE - 1)) << 20);
  }
}

__global__ void bucket_place_kernel(const int* __restrict__ bbase,
                                    const unsigned* __restrict__ packed,
                                    int* __restrict__ csr_src, int* __restrict__ rowptr,
                                    float* __restrict__ dinv, float* __restrict__ dinv2,
                                    int N, int nbuckets) {
  __shared__ int cnt[BRANGE];
  __shared__ int sh[BRANGE];
  __shared__ int cur[BRANGE];
  int b = blockIdx.x;
  int base = b << BSHIFT;
  int range_n = min(BRANGE, N - base);
  int t = threadIdx.x;           // TPB == BRANGE
  cnt[t] = 0;
  __syncthreads();
  int beg = bbase[b], end = bbase[b + 1];
  for (int e = beg + t; e < end; e += TPB)
    atomicAdd(&cnt[packed[e] >> 20], 1);
  __syncthreads();
  sh[t] = cnt[t];
  __syncthreads();
  for (int ofs = 1; ofs < BRANGE; ofs <<= 1) {
    int v = (t >= ofs) ? sh[t - ofs] : 0;
    __syncthreads();
    sh[t] += v;
    __syncthreads();
  }
  int excl = (t == 0) ? 0 : sh[t - 1];
  cur[t] = beg + excl;
  if (t < range_n) {
    rowptr[base + t] = beg + excl;
    float d = (float)(cnt[t] + 1);
    float di = 1.0f / sqrtf(d);          // identical expression to reference path
    dinv[base + t] = di;
    dinv2[base + t] = di * di;
  }
  if (b == nbuckets - 1 && t == 0) rowptr[N] = end;
  __syncthreads();
  for (int e = beg + t; e < end; e += TPB) {
    unsigned p = packed[e];
    int dstoff = (int)(p >> 20);
    int s = (int)(p & 0xFFFFFu);
    int pos = atomicAdd(&cur[dstoff], 1);
    csr_src[pos] = s;
  }
}

// ---------------- dense ops (fp64 accumulate, fp32 materialize) ----------------
// 4-unrolled with float4 A loads; k-ascending order preserved (bit-identical).
template <int K, int J>
__global__ void matmul_kernel(const float* __restrict__ A, const float* __restrict__ W,
                              float* __restrict__ out, int N) {
  int t = blockIdx.x * blockDim.x + threadIdx.x;
  if (t >= N * J) return;
  int n = t / J, j = t % J;
  const f32x4* a4 = (const f32x4*)(A + (size_t)n * K);
  double acc = 0.0;
#pragma unroll
  for (int k4 = 0; k4 < K / 4; ++k4) {
    f32x4 av = a4[k4];
    int k = k4 * 4;
    acc += (double)av.x * (double)W[(k + 0) * J + j];
    acc += (double)av.y * (double)W[(k + 1) * J + j];
    acc += (double)av.z * (double)W[(k + 2) * J + j];
    acc += (double)av.w * (double)W[(k + 3) * J + j];
  }
  out[(size_t)n * J + j] = (float)acc;
}

// gather aggregation + self-loop + bias; lane = (node, channel-quad).
// Per-channel edge order identical to the scalar version -> bit-identical fp64 sum.
template <int J>
__global__ void gather_agg_kernel(const int* __restrict__ rowptr,
                                  const int* __restrict__ csr_src,
                                  const float* __restrict__ dinv,
                                  const float* __restrict__ h,
                                  const float* __restrict__ dinv2,
                                  const float* __restrict__ b,
                                  float* __restrict__ out, int N) {
  constexpr int Q = J / 4;                 // quads per node
  int t = blockIdx.x * blockDim.x + threadIdx.x;
  int n = t / Q, q = t % Q;
  if (n >= N) return;
  const f32x4* h4 = (const f32x4*)h;       // row stride Q
  int beg = rowptr[n], end = rowptr[n + 1];
  float dn = dinv[n];
  double a0 = 0.0, a1 = 0.0, a2 = 0.0, a3 = 0.0;
  int i = beg;
  for (; i + 8 <= end; i += 8) {
    int s0 = __builtin_nontemporal_load(csr_src + i + 0);
    int s1 = __builtin_nontemporal_load(csr_src + i + 1);
    int s2 = __builtin_nontemporal_load(csr_src + i + 2);
    int s3 = __builtin_nontemporal_load(csr_src + i + 3);
    int s4 = __builtin_nontemporal_load(csr_src + i + 4);
    int s5 = __builtin_nontemporal_load(csr_src + i + 5);
    int s6 = __builtin_nontemporal_load(csr_src + i + 6);
    int s7 = __builtin_nontemporal_load(csr_src + i + 7);
    f32x4 g0 = h4[(size_t)s0 * Q + q];
    f32x4 g1 = h4[(size_t)s1 * Q + q];
    f32x4 g2 = h4[(size_t)s2 * Q + q];
    f32x4 g3 = h4[(size_t)s3 * Q + q];
    f32x4 g4 = h4[(size_t)s4 * Q + q];
    f32x4 g5 = h4[(size_t)s5 * Q + q];
    f32x4 g6 = h4[(size_t)s6 * Q + q];
    f32x4 g7 = h4[(size_t)s7 * Q + q];
    float w0 = dinv[s0] * dn, w1 = dinv[s1] * dn, w2 = dinv[s2] * dn, w3 = dinv[s3] * dn;
    float w4 = dinv[s4] * dn, w5 = dinv[s5] * dn, w6 = dinv[s6] * dn, w7 = dinv[s7] * dn;
    a0 += (double)g0.x * (double)w0; a1 += (double)g0.y * (double)w0;
    a2 += (double)g0.z * (double)w0; a3 += (double)g0.w * (double)w0;
    a0 += (double)g1.x * (double)w1; a1 += (double)g1.y * (double)w1;
    a2 += (double)g1.z * (double)w1; a3 += (double)g1.w * (double)w1;
    a0 += (double)g2.x * (double)w2; a1 += (double)g2.y * (double)w2;
    a2 += (double)g2.z * (double)w2; a3 += (double)g2.w * (double)w2;
    a0 += (double)g3.x * (double)w3; a1 += (double)g3.y * (double)w3;
    a2 += (double)g3.z * (double)w3; a3 += (double)g3.w * (double)w3;
    a0 += (double)g4.x * (double)w4; a1 += (double)g4.y * (double)w4;
    a2 += (double)g4.z * (double)w4; a3 += (double)g4.w * (double)w4;
    a0 += (double)g5.x * (double)w5; a1 += (double)g5.y * (double)w5;
    a2 += (double)g5.z * (double)w5; a3 += (double)g5.w * (double)w5;
    a0 += (double)g6.x * (double)w6; a1 += (double)g6.y * (double)w6;
    a2 += (double)g6.z * (double)w6; a3 += (double)g6.w * (double)w6;
    a0 += (double)g7.x * (double)w7; a1 += (double)g7.y * (double)w7;
    a2 += (double)g7.z * (double)w7; a3 += (double)g7.w * (double)w7;
  }
  for (; i < end; ++i) {
    int s = csr_src[i];
    float w = dinv[s] * dn;
    f32x4 g = h4[(size_t)s * Q + q];
    a0 += (double)g.x * (double)w; a1 += (double)g.y * (double)w;
    a2 += (double)g.z * (double)w; a3 += (double)g.w * (double)w;
  }
  double d2 = (double)dinv2[n];
  f32x4 gs = h4[(size_t)n * Q + q];
  a0 += (double)gs.x * d2; a1 += (double)gs.y * d2;
  a2 += (double)gs.z * d2; a3 += (double)gs.w * d2;
  int j = q * 4;
  f32x4 r;
  r.x = (float)a0 + b[j + 0];
  r.y = (float)a1 + b[j + 1];
  r.z = (float)a2 + b[j + 2];
  r.w = (float)a3 + b[j + 3];
  __builtin_nontemporal_store(r, (f32x4*)(out + (size_t)n * J + j));
}

// ---------------- heads (phase 1: hidden layers, exact fp32 materialization) ----
__global__ void hid_start_kernel(const float* __restrict__ h,
                                 const float* __restrict__ Ws1, const float* __restrict__ bs1,
                                 float* __restrict__ hid, int N) {
  int t = blockIdx.x * blockDim.x + threadIdx.x;
  if (t >= N * 16) return;
  int n = t / 16, j = t % 16;
  const float* hr = h + (size_t)n * 32;
  double a = 0.0;
#pragma unroll
  for (int k = 0; k < 32; ++k) a += (double)hr[k] * (double)Ws1[k * 16 + j];
  float v = (float)a + bs1[j];
  hid[t] = fminf(fmaxf(v, 0.0f), 6.0f);
}

__global__ void hid_end_kernel(const float* __restrict__ h, const int* __restrict__ start,
                               const float* __restrict__ We1, const float* __restrict__ be1,
                               float* __restrict__ hid, int N) {
  int t = blockIdx.x * blockDim.x + threadIdx.x;
  if (t >= 2 * N * 24) return;
  int r = t / 24, j = t % 24;
  int row = (r < N) ? r : start[r - N];
  const float* hr = h + (size_t)row * 32;
  double a = 0.0;
#pragma unroll
  for (int k = 0; k < 32; ++k) a += (double)hr[k] * (double)We1[k * 24 + j];
  float v = (float)a + be1[j];
  hid[t] = fminf(fmaxf(v, 0.0f), 6.0f);
}

// ------------- heads (phase 2: fast fp32 logits+gumbel, exact fp64 fallback) ----
template <int K>
__global__ void pick_kernel(const float* __restrict__ hid,
                            const float* __restrict__ W2, const float* __restrict__ b2,
                            int* __restrict__ outw, int R, unsigned k0, unsigned k1) {
  int t = blockIdx.x * blockDim.x + threadIdx.x;
  int r = t >> 5;            // row
  int c = t & 31;            // class
  if (r >= R) return;
  const float* hr = hid + (size_t)r * K;

  // ---- fast path: fp32 dot + fp32 gumbel ----
  float af = 0.0f;
#pragma unroll
  for (int k = 0; k < K; ++k) af = fmaf(hr[k], W2[k * 32 + c], af);
  float zf = af + b2[c] + gumbel_fast(k0, k1, (unsigned)(r * 32 + c));

  // butterfly top-2 (m1,i1 = max w/ lower-index tie-break; m2 = runner-up value)
  float m1 = zf; int i1 = c; float m2 = -INFINITY;
#pragma unroll
  for (int m = 16; m >= 1; m >>= 1) {
    float om1 = __shfl_xor(m1, m, 32);
    int   oi1 = __shfl_xor(i1, m, 32);
    float om2 = __shfl_xor(m2, m, 32);
    if (om1 > m1 || (om1 == m1 && oi1 < i1)) {
      m2 = fmaxf(m1, om2);
      m1 = om1; i1 = oi1;
    } else {
      m2 = fmaxf(m2, om1);
    }
  }

  if (m1 - m2 >= 1e-3f) {            // safe: fast argmax == exact argmax
    if (c == 0) outw[r] = i1;
    return;
  }

  // ---- exact fallback (rare): fp64 dot + fp64-log gumbel, original argmax ----
  double a = 0.0;
#pragma unroll
  for (int k = 0; k < K; ++k) a += (double)hr[k] * (double)W2[k * 32 + c];
  float logit = (float)a + b2[c];
  float z = logit + gumbel_exact(k0, k1, (unsigned)(r * 32 + c));
  int best = c;
#pragma unroll
  for (int m = 16; m >= 1; m >>= 1) {
    float oz = __shfl_xor(z, m, 32);
    int   ob = __shfl_xor(best, m, 32);
    if (oz > z || (oz == z && ob < best)) { z = oz; best = ob; }
  }
  if (c == 0) outw[r] = best;
}

// ---------------- launch ----------------
extern "C" void kernel_launch(void* const* d_in, const int* in_sizes, int n_in,
                              void* d_out, int out_size, void* d_ws, size_t ws_size,
                              hipStream_t stream) {
  const float* x   = (const float*)d_in[0];
  const int*   ei  = (const int*)d_in[1];     // [2, E] int32
  const float* W1  = (const float*)d_in[3];
  const float* b1  = (const float*)d_in[4];
  const float* W2  = (const float*)d_in[5];
  const float* b2  = (const float*)d_in[6];
  const float* W3  = (const float*)d_in[7];
  const float* b3  = (const float*)d_in[8];
  const float* Ws1 = (const float*)d_in[9];
  const float* bs1 = (const float*)d_in[10];
  const float* Ws2 = (const float*)d_in[11];
  const float* bs2 = (const float*)d_in[12];
  const float* We1 = (const float*)d_in[13];
  const float* be1 = (const float*)d_in[14];
  const float* We2 = (const float*)d_in[15];
  const float* be2 = (const float*)d_in[16];

  const int N = in_sizes[0] / 128;
  const int E = in_sizes[1] / 2;
  const int* srcv = ei;
  const int* dstv = ei + E;
  const int nbuckets = (N + BRANGE - 1) >> BSHIFT;
  const int nblk = (E + CHUNK - 1) / CHUNK;

  char* ws = (char*)d_ws;
  size_t off = 0;
  float*    hA      = (float*)(ws + off);    off += (size_t)N * 32 * 4;
  float*    hB      = (float*)(ws + off);    off += (size_t)N * 32 * 4;
  int*      csr_src = (int*)(ws + off);      off += (size_t)E * 4;
  unsigned* packed  = (unsigned*)(ws + off); off += (size_t)E * 4;
  float*    dinv    = (float*)(ws + off);    off += (size_t)N * 4;
  float*    dinv2   = (float*)(ws + off);    off += (size_t)N * 4;
  int*      rowptr  = (int*)(ws + off);      off += (size_t)(N + 1) * 4;
  int*      histT   = (int*)(ws + off);      off += (size_t)nbuckets * nblk * 4;
  int*      btot    = (int*)(ws + off);      off += (size_t)MAXB * 4;
  int*      bbase   = (int*)(ws + off);      off += (size_t)(MAXB + 1) * 4;
  // head-phase overlays (dead regions by then)
  float* hid_start = hA;               // N*16 fp32 fits in hA (N*32)
  float* hid_end   = (float*)csr_src;  // 2N*24*4 = 19.2MB fits in csr_src+packed (25.6MB)

  unsigned k1a, k1b, k2a, k2b;
  tf2x32(0u, 42u, 0u, 0u, k1a, k1b);
  tf2x32(0u, 42u, 0u, 1u, k2a, k2b);

  // CSR build: hist -> colscan -> bucketscan -> place -> bucket_place
  hist_kernel<<<nblk, TPB, 0, stream>>>(dstv, histT, E, nblk, nbuckets);
  colscan_kernel<<<nbuckets, MAXB, 0, stream>>>(histT, btot, nblk);
  bucketscan_kernel<<<1, MAXB, 0, stream>>>(btot, bbase, nbuckets, E);
  place_kernel<<<nblk, TPB, 0, stream>>>(srcv, dstv, histT, bbase, packed, E, nblk, nbuckets);
  bucket_place_kernel<<<nbuckets, TPB, 0, stream>>>(bbase, packed, csr_src, rowptr,
                                                    dinv, dinv2, N, nbuckets);

  // Layer 1: 128 -> 16   (x -> hA -> hB)
  matmul_kernel<128, 16><<<((size_t)N * 16 + TPB - 1) / TPB, TPB, 0, stream>>>(x, W1, hA, N);
  gather_agg_kernel<16><<<((size_t)N * 4 + TPB - 1) / TPB, TPB, 0, stream>>>(
      rowptr, csr_src, dinv, hA, dinv2, b1, hB, N);

  // Layer 2: 16 -> 24    (hB -> hA -> hB)
  matmul_kernel<16, 24><<<((size_t)N * 24 + TPB - 1) / TPB, TPB, 0, stream>>>(hB, W2, hA, N);
  gather_agg_kernel<24><<<((size_t)N * 6 + TPB - 1) / TPB, TPB, 0, stream>>>(
      rowptr, csr_src, dinv, hA, dinv2, b2, hB, N);

  // Layer 3: 24 -> 32    (hB -> hA -> hB)
  matmul_kernel<24, 32><<<((size_t)N * 32 + TPB - 1) / TPB, TPB, 0, stream>>>(hB, W3, hA, N);
  gather_agg_kernel<32><<<((size_t)N * 8 + TPB - 1) / TPB, TPB, 0, stream>>>(
      rowptr, csr_src, dinv, hA, dinv2, b3, hB, N);

  int* outI = (int*)d_out;

  // Start head
  hid_start_kernel<<<((size_t)N * 16 + TPB - 1) / TPB, TPB, 0, stream>>>(hB, Ws1, bs1, hid_start, N);
  pick_kernel<16><<<((size_t)N * 32 + TPB - 1) / TPB, TPB, 0, stream>>>(
      hid_start, Ws2, bs2, outI, N, k1a, k1b);

  // End head
  hid_end_kernel<<<((size_t)2 * N * 24 + TPB - 1) / TPB, TPB, 0, stream>>>(hB, outI, We1, be1, hid_end, N);
  pick_kernel<24><<<((size_t)2 * N * 32 + TPB - 1) / TPB, TPB, 0, stream>>>(
      hid_end, We2, be2, outI + N, 2 * N, k2a, k2b);
}

// Round 11
// 561.392 us; speedup vs baseline: 1.0790x; 1.0790x over previous
//
#include <hip/hip_runtime.h>
#include <hip/hip_bf16.h>
#include <math.h>

#define TPB 256
#define BSHIFT 8                 // 256 nodes per bucket
#define BRANGE (1 << BSHIFT)     // == TPB (bucket_place relies on this)
#define CHUNK 8192               // edges per partition block
#define MAXB 512                 // max buckets (N <= 131072)

// ---------------- Threefry2x32 (exact JAX semantics) ----------------
__host__ __device__ inline void tf2x32(unsigned ks0, unsigned ks1,
                                       unsigned x0, unsigned x1,
                                       unsigned& o0, unsigned& o1) {
  const unsigned ks2 = ks0 ^ ks1 ^ 0x1BD11BDAu;
  unsigned v0 = x0 + ks0, v1 = x1 + ks1;
#define TF_RND(r) { v0 += v1; v1 = (v1 << (r)) | (v1 >> (32 - (r))); v1 ^= v0; }
  TF_RND(13) TF_RND(15) TF_RND(26) TF_RND(6)
  v0 += ks1; v1 += ks2 + 1u;
  TF_RND(17) TF_RND(29) TF_RND(16) TF_RND(24)
  v0 += ks2; v1 += ks0 + 2u;
  TF_RND(13) TF_RND(15) TF_RND(26) TF_RND(6)
  v0 += ks0; v1 += ks1 + 3u;
  TF_RND(17) TF_RND(29) TF_RND(16) TF_RND(24)
  v0 += ks1; v1 += ks2 + 4u;
  TF_RND(13) TF_RND(15) TF_RND(26) TF_RND(6)
  v0 += ks2; v1 += ks0 + 5u;
#undef TF_RND
  o0 = v0; o1 = v1;
}

__device__ __forceinline__ unsigned bits32(unsigned k0, unsigned k1, unsigned idx) {
  unsigned o0, o1;
  tf2x32(k0, k1, 0u, idx, o0, o1);
  return o0 ^ o1;
}

__device__ __forceinline__ float bits_to_u(unsigned bits) {
  float f = __uint_as_float((bits >> 9) | 0x3f800000u) - 1.0f;
  return (f > 0.0f) ? f : 1.17549435e-38f;
}

// exact path: fp64 logs rounded to fp32 at each stage (matches ref staging)
__device__ __forceinline__ float gumbel_exact(unsigned k0, unsigned k1, unsigned idx) {
  float u = bits_to_u(bits32(k0, k1, idx));
  float w = (float)(-log((double)u));
  return (float)(-log((double)w));
}

// fast path: fp32 logs (error ~1e-6 abs; used only when argmax gap is large)
__device__ __forceinline__ float gumbel_fast(unsigned k0, unsigned k1, unsigned idx) {
  float u = bits_to_u(bits32(k0, k1, idx));
  float w = -logf(u);
  return -logf(w);
}

// ---- counting-sort partition: hist -> colscan -> bucketscan -> place ----
__global__ void hist_kernel(const int* __restrict__ dst, int* __restrict__ histT,
                            int E, int nblk, int nbuckets) {
  __shared__ int hist[MAXB];
  for (int i = threadIdx.x; i < nbuckets; i += TPB) hist[i] = 0;
  __syncthreads();
  int beg = blockIdx.x * CHUNK;
  int end = min(beg + CHUNK, E);
  for (int e = beg + threadIdx.x; e < end; e += TPB)
    atomicAdd(&hist[dst[e] >> BSHIFT], 1);
  __syncthreads();
  for (int i = threadIdx.x; i < nbuckets; i += TPB)
    histT[(size_t)i * nblk + blockIdx.x] = hist[i];
}

__global__ void colscan_kernel(int* __restrict__ histT, int* __restrict__ btot, int nblk) {
  __shared__ int sh[MAXB];
  int b = blockIdx.x;
  int t = threadIdx.x;
  sh[t] = (t < nblk) ? histT[(size_t)b * nblk + t] : 0;
  __syncthreads();
  for (int ofs = 1; ofs < MAXB; ofs <<= 1) {
    int v = (t >= ofs) ? sh[t - ofs] : 0;
    __syncthreads();
    sh[t] += v;
    __syncthreads();
  }
  if (t < nblk) histT[(size_t)b * nblk + t] = (t == 0) ? 0 : sh[t - 1];
  if (t == MAXB - 1) btot[b] = sh[MAXB - 1];
}

__global__ void bucketscan_kernel(const int* __restrict__ btot, int* __restrict__ bbase,
                                  int nbuckets, int E) {
  __shared__ int sh[MAXB];
  int t = threadIdx.x;
  sh[t] = (t < nbuckets) ? btot[t] : 0;
  __syncthreads();
  for (int ofs = 1; ofs < MAXB; ofs <<= 1) {
    int v = (t >= ofs) ? sh[t - ofs] : 0;
    __syncthreads();
    sh[t] += v;
    __syncthreads();
  }
  if (t < nbuckets) bbase[t] = (t == 0) ? 0 : sh[t - 1];
  if (t == 0) bbase[nbuckets] = E;
}

__global__ void place_kernel(const int* __restrict__ src, const int* __restrict__ dst,
                             const int* __restrict__ histT, const int* __restrict__ bbase,
                             unsigned* __restrict__ packed, int E, int nblk, int nbuckets) {
  __shared__ int cur[MAXB];
  for (int i = threadIdx.x; i < nbuckets; i += TPB)
    cur[i] = histT[(size_t)i * nblk + blockIdx.x] + bbase[i];
  __syncthreads();
  int beg = blockIdx.x * CHUNK;
  int end = min(beg + CHUNK, E);
  for (int e = beg + threadIdx.x; e < end; e += TPB) {
    int s = src[e], d = dst[e];
    int b = d >> BSHIFT;
    int pos = atomicAdd(&cur[b], 1);        // LDS atomic only
    packed[pos] = (unsigned)s | ((unsigned)(d & (BRANGE - 1)) << 20);
  }
}

__global__ void bucket_place_kernel(const int* __restrict__ bbase,
                                    const unsigned* __restrict__ packed,
                                    int* __restrict__ csr_src, int* __restrict__ rowptr,
                                    float* __restrict__ dinv, float* __restrict__ dinv2,
                                    int N, int nbuckets) {
  __shared__ int cnt[BRANGE];
  __shared__ int sh[BRANGE];
  __shared__ int cur[BRANGE];
  int b = blockIdx.x;
  int base = b << BSHIFT;
  int range_n = min(BRANGE, N - base);
  int t = threadIdx.x;           // TPB == BRANGE
  cnt[t] = 0;
  __syncthreads();
  int beg = bbase[b], end = bbase[b + 1];
  for (int e = beg + t; e < end; e += TPB)
    atomicAdd(&cnt[packed[e] >> 20], 1);
  __syncthreads();
  sh[t] = cnt[t];
  __syncthreads();
  for (int ofs = 1; ofs < BRANGE; ofs <<= 1) {
    int v = (t >= ofs) ? sh[t - ofs] : 0;
    __syncthreads();
    sh[t] += v;
    __syncthreads();
  }
  int excl = (t == 0) ? 0 : sh[t - 1];
  cur[t] = beg + excl;
  if (t < range_n) {
    rowptr[base + t] = beg + excl;
    float d = (float)(cnt[t] + 1);
    float di = 1.0f / sqrtf(d);          // identical expression to reference path
    dinv[base + t] = di;
    dinv2[base + t] = di * di;
  }
  if (b == nbuckets - 1 && t == 0) rowptr[N] = end;
  __syncthreads();
  for (int e = beg + t; e < end; e += TPB) {
    unsigned p = packed[e];
    int dstoff = (int)(p >> 20);
    int s = (int)(p & 0xFFFFFu);
    int pos = atomicAdd(&cur[dstoff], 1);
    csr_src[pos] = s;
  }
}

// ---------------- dense ops (fp64 accumulate, fp32 materialize) ----------------
template <int K, int J>
__global__ void matmul_kernel(const float* __restrict__ A, const float* __restrict__ W,
                              float* __restrict__ out, int N) {
  int t = blockIdx.x * blockDim.x + threadIdx.x;
  if (t >= N * J) return;
  int n = t / J, j = t % J;
  const float* a = A + (size_t)n * K;
  double acc = 0.0;
  for (int k = 0; k < K; ++k) acc += (double)a[k] * (double)W[k * J + j];
  out[(size_t)n * J + j] = (float)acc;
}

// gather aggregation for J in {16,32}: lane group of J lanes shares one node.
// Per chunk of J edges: lane j loads csr_src[i+j] (coalesced) + dinv[s_j] (one
// gather), then shfl-broadcasts (s,w) from registers; h loads issue back-to-back.
// Ascending-i fp64 accumulation, w = dinv[s]*dn in fp32 -> bit-identical to R8.
template <int J>
__global__ void gather_shfl_kernel(const int* __restrict__ rowptr,
                                   const int* __restrict__ csr_src,
                                   const float* __restrict__ dinv,
                                   const float* __restrict__ h,
                                   const float* __restrict__ dinv2,
                                   const float* __restrict__ b,
                                   float* __restrict__ out, int N) {
  int t = blockIdx.x * blockDim.x + threadIdx.x;
  int n = t / J, j = t % J;
  if (n >= N) return;
  int beg = rowptr[n], end = rowptr[n + 1];
  float dn = dinv[n];
  double acc = 0.0;
  for (int i = beg; i < end; i += J) {
    int m = end - i; if (m > J) m = J;
    int idx = i + j; if (idx >= end) idx = end - 1;
    int   sj = csr_src[idx];
    float wj = dinv[sj];
    int k = 0;
    for (; k + 8 <= m; k += 8) {
      int s0 = __shfl(sj, k + 0, J), s1 = __shfl(sj, k + 1, J);
      int s2 = __shfl(sj, k + 2, J), s3 = __shfl(sj, k + 3, J);
      int s4 = __shfl(sj, k + 4, J), s5 = __shfl(sj, k + 5, J);
      int s6 = __shfl(sj, k + 6, J), s7 = __shfl(sj, k + 7, J);
      float w0 = __shfl(wj, k + 0, J) * dn, w1 = __shfl(wj, k + 1, J) * dn;
      float w2 = __shfl(wj, k + 2, J) * dn, w3 = __shfl(wj, k + 3, J) * dn;
      float w4 = __shfl(wj, k + 4, J) * dn, w5 = __shfl(wj, k + 5, J) * dn;
      float w6 = __shfl(wj, k + 6, J) * dn, w7 = __shfl(wj, k + 7, J) * dn;
      float g0 = h[(size_t)s0 * J + j], g1 = h[(size_t)s1 * J + j];
      float g2 = h[(size_t)s2 * J + j], g3 = h[(size_t)s3 * J + j];
      float g4 = h[(size_t)s4 * J + j], g5 = h[(size_t)s5 * J + j];
      float g6 = h[(size_t)s6 * J + j], g7 = h[(size_t)s7 * J + j];
      acc += (double)g0 * (double)w0;
      acc += (double)g1 * (double)w1;
      acc += (double)g2 * (double)w2;
      acc += (double)g3 * (double)w3;
      acc += (double)g4 * (double)w4;
      acc += (double)g5 * (double)w5;
      acc += (double)g6 * (double)w6;
      acc += (double)g7 * (double)w7;
    }
    for (; k < m; ++k) {
      int   s = __shfl(sj, k, J);
      float w = __shfl(wj, k, J) * dn;
      acc += (double)h[(size_t)s * J + j] * (double)w;
    }
  }
  acc += (double)h[(size_t)n * J + j] * (double)dinv2[n];
  out[(size_t)n * J + j] = (float)acc + b[j];
}

// R8 scalar gather (kept for J=24, where shuffle width isn't a power of 2)
template <int J>
__global__ void gather_agg_kernel(const int* __restrict__ rowptr,
                                  const int* __restrict__ csr_src,
                                  const float* __restrict__ dinv,
                                  const float* __restrict__ h,
                                  const float* __restrict__ dinv2,
                                  const float* __restrict__ b,
                                  float* __restrict__ out, int N) {
  int t = blockIdx.x * blockDim.x + threadIdx.x;
  int n = t / J, j = t % J;
  if (n >= N) return;
  int beg = rowptr[n], end = rowptr[n + 1];
  float dn = dinv[n];
  double acc = 0.0;
  int i = beg;
  for (; i + 8 <= end; i += 8) {
    int s0 = csr_src[i + 0], s1 = csr_src[i + 1], s2 = csr_src[i + 2], s3 = csr_src[i + 3];
    int s4 = csr_src[i + 4], s5 = csr_src[i + 5], s6 = csr_src[i + 6], s7 = csr_src[i + 7];
    float g0 = h[(size_t)s0 * J + j], g1 = h[(size_t)s1 * J + j];
    float g2 = h[(size_t)s2 * J + j], g3 = h[(size_t)s3 * J + j];
    float g4 = h[(size_t)s4 * J + j], g5 = h[(size_t)s5 * J + j];
    float g6 = h[(size_t)s6 * J + j], g7 = h[(size_t)s7 * J + j];
    float w0 = dinv[s0] * dn, w1 = dinv[s1] * dn, w2 = dinv[s2] * dn, w3 = dinv[s3] * dn;
    float w4 = dinv[s4] * dn, w5 = dinv[s5] * dn, w6 = dinv[s6] * dn, w7 = dinv[s7] * dn;
    acc += (double)g0 * (double)w0;
    acc += (double)g1 * (double)w1;
    acc += (double)g2 * (double)w2;
    acc += (double)g3 * (double)w3;
    acc += (double)g4 * (double)w4;
    acc += (double)g5 * (double)w5;
    acc += (double)g6 * (double)w6;
    acc += (double)g7 * (double)w7;
  }
  for (; i < end; ++i) {
    int s = csr_src[i];
    float w = dinv[s] * dn;
    acc += (double)h[(size_t)s * J + j] * (double)w;
  }
  acc += (double)h[(size_t)n * J + j] * (double)dinv2[n];
  out[(size_t)n * J + j] = (float)acc + b[j];
}

// ---------------- heads (phase 1: hidden layers, exact fp32 materialization) ----
__global__ void hid_start_kernel(const float* __restrict__ h,
                                 const float* __restrict__ Ws1, const float* __restrict__ bs1,
                                 float* __restrict__ hid, int N) {
  int t = blockIdx.x * blockDim.x + threadIdx.x;
  if (t >= N * 16) return;
  int n = t / 16, j = t % 16;
  const float* hr = h + (size_t)n * 32;
  double a = 0.0;
#pragma unroll
  for (int k = 0; k < 32; ++k) a += (double)hr[k] * (double)Ws1[k * 16 + j];
  float v = (float)a + bs1[j];
  hid[t] = fminf(fmaxf(v, 0.0f), 6.0f);
}

__global__ void hid_end_kernel(const float* __restrict__ h, const int* __restrict__ start,
                               const float* __restrict__ We1, const float* __restrict__ be1,
                               float* __restrict__ hid, int N) {
  int t = blockIdx.x * blockDim.x + threadIdx.x;
  if (t >= 2 * N * 24) return;
  int r = t / 24, j = t % 24;
  int row = (r < N) ? r : start[r - N];
  const float* hr = h + (size_t)row * 32;
  double a = 0.0;
#pragma unroll
  for (int k = 0; k < 32; ++k) a += (double)hr[k] * (double)We1[k * 24 + j];
  float v = (float)a + be1[j];
  hid[t] = fminf(fmaxf(v, 0.0f), 6.0f);
}

// ------------- heads (phase 2: fast fp32 logits+gumbel, exact fp64 fallback) ----
template <int K>
__global__ void pick_kernel(const float* __restrict__ hid,
                            const float* __restrict__ W2, const float* __restrict__ b2,
                            int* __restrict__ outw, int R, unsigned k0, unsigned k1) {
  int t = blockIdx.x * blockDim.x + threadIdx.x;
  int r = t >> 5;            // row
  int c = t & 31;            // class
  if (r >= R) return;
  const float* hr = hid + (size_t)r * K;

  // ---- fast path: fp32 dot + fp32 gumbel ----
  float af = 0.0f;
#pragma unroll
  for (int k = 0; k < K; ++k) af = fmaf(hr[k], W2[k * 32 + c], af);
  float zf = af + b2[c] + gumbel_fast(k0, k1, (unsigned)(r * 32 + c));

  // butterfly top-2 (m1,i1 = max w/ lower-index tie-break; m2 = runner-up value)
  float m1 = zf; int i1 = c; float m2 = -INFINITY;
#pragma unroll
  for (int m = 16; m >= 1; m >>= 1) {
    float om1 = __shfl_xor(m1, m, 32);
    int   oi1 = __shfl_xor(i1, m, 32);
    float om2 = __shfl_xor(m2, m, 32);
    if (om1 > m1 || (om1 == m1 && oi1 < i1)) {
      m2 = fmaxf(m1, om2);
      m1 = om1; i1 = oi1;
    } else {
      m2 = fmaxf(m2, om1);
    }
  }

  if (m1 - m2 >= 1e-3f) {            // safe: fast argmax == exact argmax
    if (c == 0) outw[r] = i1;
    return;
  }

  // ---- exact fallback (rare): fp64 dot + fp64-log gumbel, original argmax ----
  double a = 0.0;
#pragma unroll
  for (int k = 0; k < K; ++k) a += (double)hr[k] * (double)W2[k * 32 + c];
  float logit = (float)a + b2[c];
  float z = logit + gumbel_exact(k0, k1, (unsigned)(r * 32 + c));
  int best = c;
#pragma unroll
  for (int m = 16; m >= 1; m >>= 1) {
    float oz = __shfl_xor(z, m, 32);
    int   ob = __shfl_xor(best, m, 32);
    if (oz > z || (oz == z && ob < best)) { z = oz; best = ob; }
  }
  if (c == 0) outw[r] = best;
}

// ---------------- launch ----------------
extern "C" void kernel_launch(void* const* d_in, const int* in_sizes, int n_in,
                              void* d_out, int out_size, void* d_ws, size_t ws_size,
                              hipStream_t stream) {
  const float* x   = (const float*)d_in[0];
  const int*   ei  = (const int*)d_in[1];     // [2, E] int32
  const float* W1  = (const float*)d_in[3];
  const float* b1  = (const float*)d_in[4];
  const float* W2  = (const float*)d_in[5];
  const float* b2  = (const float*)d_in[6];
  const float* W3  = (const float*)d_in[7];
  const float* b3  = (const float*)d_in[8];
  const float* Ws1 = (const float*)d_in[9];
  const float* bs1 = (const float*)d_in[10];
  const float* Ws2 = (const float*)d_in[11];
  const float* bs2 = (const float*)d_in[12];
  const float* We1 = (const float*)d_in[13];
  const float* be1 = (const float*)d_in[14];
  const float* We2 = (const float*)d_in[15];
  const float* be2 = (const float*)d_in[16];

  const int N = in_sizes[0] / 128;
  const int E = in_sizes[1] / 2;
  const int* srcv = ei;
  const int* dstv = ei + E;
  const int nbuckets = (N + BRANGE - 1) >> BSHIFT;
  const int nblk = (E + CHUNK - 1) / CHUNK;

  char* ws = (char*)d_ws;
  size_t off = 0;
  float*    hA      = (float*)(ws + off);    off += (size_t)N * 32 * 4;
  float*    hB      = (float*)(ws + off);    off += (size_t)N * 32 * 4;
  int*      csr_src = (int*)(ws + off);      off += (size_t)E * 4;
  unsigned* packed  = (unsigned*)(ws + off); off += (size_t)E * 4;
  float*    dinv    = (float*)(ws + off);    off += (size_t)N * 4;
  float*    dinv2   = (float*)(ws + off);    off += (size_t)N * 4;
  int*      rowptr  = (int*)(ws + off);      off += (size_t)(N + 1) * 4;
  int*      histT   = (int*)(ws + off);      off += (size_t)nbuckets * nblk * 4;
  int*      btot    = (int*)(ws + off);      off += (size_t)MAXB * 4;
  int*      bbase   = (int*)(ws + off);      off += (size_t)(MAXB + 1) * 4;
  // head-phase overlays (dead regions by then)
  float* hid_start = hA;               // N*16 fp32 fits in hA (N*32)
  float* hid_end   = (float*)csr_src;  // 2N*24*4 = 19.2MB fits in csr_src+packed (25.6MB)

  unsigned k1a, k1b, k2a, k2b;
  tf2x32(0u, 42u, 0u, 0u, k1a, k1b);
  tf2x32(0u, 42u, 0u, 1u, k2a, k2b);

  // CSR build: hist -> colscan -> bucketscan -> place -> bucket_place
  hist_kernel<<<nblk, TPB, 0, stream>>>(dstv, histT, E, nblk, nbuckets);
  colscan_kernel<<<nbuckets, MAXB, 0, stream>>>(histT, btot, nblk);
  bucketscan_kernel<<<1, MAXB, 0, stream>>>(btot, bbase, nbuckets, E);
  place_kernel<<<nblk, TPB, 0, stream>>>(srcv, dstv, histT, bbase, packed, E, nblk, nbuckets);
  bucket_place_kernel<<<nbuckets, TPB, 0, stream>>>(bbase, packed, csr_src, rowptr,
                                                    dinv, dinv2, N, nbuckets);

  // Layer 1: 128 -> 16   (x -> hA -> hB)
  matmul_kernel<128, 16><<<((size_t)N * 16 + TPB - 1) / TPB, TPB, 0, stream>>>(x, W1, hA, N);
  gather_shfl_kernel<16><<<((size_t)N * 16 + TPB - 1) / TPB, TPB, 0, stream>>>(
      rowptr, csr_src, dinv, hA, dinv2, b1, hB, N);

  // Layer 2: 16 -> 24    (hB -> hA -> hB)
  matmul_kernel<16, 24><<<((size_t)N * 24 + TPB - 1) / TPB, TPB, 0, stream>>>(hB, W2, hA, N);
  gather_agg_kernel<24><<<((size_t)N * 24 + TPB - 1) / TPB, TPB, 0, stream>>>(
      rowptr, csr_src, dinv, hA, dinv2, b2, hB, N);

  // Layer 3: 24 -> 32    (hB -> hA -> hB)
  matmul_kernel<24, 32><<<((size_t)N * 32 + TPB - 1) / TPB, TPB, 0, stream>>>(hB, W3, hA, N);
  gather_shfl_kernel<32><<<((size_t)N * 32 + TPB - 1) / TPB, TPB, 0, stream>>>(
      rowptr, csr_src, dinv, hA, dinv2, b3, hB, N);

  int* outI = (int*)d_out;

  // Start head
  hid_start_kernel<<<((size_t)N * 16 + TPB - 1) / TPB, TPB, 0, stream>>>(hB, Ws1, bs1, hid_start, N);
  pick_kernel<16><<<((size_t)N * 32 + TPB - 1) / TPB, TPB, 0, stream>>>(
      hid_start, Ws2, bs2, outI, N, k1a, k1b);

  // End head
  hid_end_kernel<<<((size_t)2 * N * 24 + TPB - 1) / TPB, TPB, 0, stream>>>(hB, outI, We1, be1, hid_end, N);
  pick_kernel<24><<<((size_t)2 * N * 32 + TPB - 1) / TPB, TPB, 0, stream>>>(
      hid_end, We2, be2, outI + N, 2 * N, k2a, k2b);
}